// Round 3
// baseline (265.702 us; speedup 1.0000x reference)
//
#include <hip/hip_runtime.h>

// MinimalRNNCell on MI355X (gfx950).  h_t = x_t@W + h_{t-1}@A, B=32,T=1024,D=U=512, fp32.
//
// R8: collapse 3 big passes -> 2 (radix-4x4 over the 16 validated taps).
// R7 evidence: each big pass is latency-bound (~50-60us at MfmaUtil 18-24%) regardless of
// FLOP content -> time scales with pass COUNT. New structure:
//   P[t]   = x_t W + x_{t-1} WA + x_{t-2} WA^2 + x_{t-3} WA^3     (4 taps, 32 MFMA/chunk)
//   OUT[t] = P[t] + P[t-4] A^4 + P[t-8] A^8 + P[t-12] A^12        (tap-0 via staged tile)
// Same sum over taps 0..15 (k=4m+j), one fewer f16 rounding stage. +17 GFLOP, -1 big pass,
// -34MB P round-trip. Keeps R7's XCD-affinity remap + prefetch-2 register staging.
// P lives in ws (pass2 reads it while writing f32 to d_out). Power chain needs 4 small
// GEMM launches: L1{WA,A2} L2{WA2,WA3,A4} L3{A8} L4{A12}.
// P buffer: f16, padded 16 zero rows per batch (pad zeroed by pass1 t0==0 WGs; H=12<=16).

typedef _Float16 f16;
typedef _Float16 f16x8 __attribute__((ext_vector_type(8)));
typedef float f32x16 __attribute__((ext_vector_type(16)));

#define PROW 1040
#define PBSTRIDE ((size_t)PROW * 512)
#define MFMA __builtin_amdgcn_mfma_f32_32x32x16_f16

__device__ __forceinline__ int rowOf(int r, int Lh) { return (r & 3) + 8 * (r >> 2) + 4 * Lh; }
__device__ __forceinline__ size_t fragOff(int kbG, int ntG, int L, int j) {
  // B-frag layout: frag[kbG][ntG][L][j] = M[kbG*16 + (L>>5)*8 + j][ntG*32 + (L&31)]
  return (((size_t)(kbG * 16 + ntG) * 64) + L) * 8 + j;
}
__device__ __forceinline__ void barrier_lgkm() {
  asm volatile("s_waitcnt lgkmcnt(0)\n\ts_barrier" ::: "memory");
}
// XCD-affinity remap for grid 2048 (2048%8==0 -> bijective): slots with equal s%8 land on
// the same XCD; consecutive logical ids (the 4 q-WGs of a tile) share one XCD-L2.
__device__ __forceinline__ int xcdRemap(int s) { return (s & 7) * 256 + (s >> 3); }

// ---------------------------------------------------------------------------
// Kc1: W,A (f32 [k][n]) -> plain f16 + B-fragment f16. blocks 0..63: W; 64..127: A.
__global__ void Kc1(const float* __restrict__ W, const float* __restrict__ A,
                    f16* Wh, f16* Ah, f16* Wf, f16* Af) {
  const bool isA = blockIdx.x >= 64;
  const float* src = isA ? A : W;
  f16* plain = isA ? Ah : Wh;
  f16* frag  = isA ? Af : Wf;
  int thrG = (blockIdx.x & 63) * 256 + threadIdx.x;
  {
    size_t base = (size_t)thrG * 16;
    f16x8 v0, v1;
#pragma unroll
    for (int j = 0; j < 8; ++j) { v0[j] = (f16)src[base + j]; v1[j] = (f16)src[base + 8 + j]; }
    *(f16x8*)(plain + base) = v0;
    *(f16x8*)(plain + base + 8) = v1;
  }
#pragma unroll
  for (int blk = 0; blk < 2; ++blk) {
    size_t f = (size_t)thrG * 16 + blk * 8;
    int L = (int)((f >> 3) & 63), ntG = (int)((f >> 9) & 15), kbG = (int)(f >> 13);
    int k0 = kbG * 16 + (L >> 5) * 8, n = ntG * 32 + (L & 31);
    f16x8 v;
#pragma unroll
    for (int j = 0; j < 8; ++j) v[j] = (f16)src[(size_t)(k0 + j) * 512 + n];
    *(f16x8*)(frag + f) = v;
  }
}

// ---------------------------------------------------------------------------
// Gk3: up to three 512x512 GEMM jobs (C = Ap x Bf), job = blockIdx>>5, 32 WG each.
__global__ __launch_bounds__(256) void Gk3(const f16* __restrict__ Ap0, const f16* __restrict__ Bf0,
                                           f16* P0, f16* F0,
                                           const f16* __restrict__ Ap1, const f16* __restrict__ Bf1,
                                           f16* P1o, f16* F1,
                                           const f16* __restrict__ Ap2, const f16* __restrict__ Bf2,
                                           f16* P2o, f16* F2) {
  __shared__ __align__(16) char lds[65536];
  const int job = blockIdx.x >> 5;
  const f16* Ap = (job == 0) ? Ap0 : (job == 1) ? Ap1 : Ap2;
  const f16* Bf = (job == 0) ? Bf0 : (job == 1) ? Bf1 : Bf2;
  f16* outP = (job == 0) ? P0 : (job == 1) ? P1o : P2o;
  f16* outF = (job == 0) ? F0 : (job == 1) ? F1 : F2;
  const int bid = blockIdx.x & 31;
  const int tid = threadIdx.x;
  const int w = tid >> 6, L = tid & 63, Lm = L & 31, Lh = L >> 5;
  const int mt64 = bid >> 2, n0 = (bid & 3) * 128;
  {
    int m = tid >> 2, q = tid & 3;
    const f16* srcp = Ap + (size_t)(mt64 * 64 + m) * 512 + q * 128;
    char* wb = lds + m * 16;
#pragma unroll
    for (int j = 0; j < 16; ++j)
      *(f16x8*)(wb + (q * 16 + j) * 1024) = *(const f16x8*)(srcp + j * 8);
  }
  __syncthreads();
  const int ntG = (n0 >> 5) + w;
  f32x16 acc[2] = {};
#pragma unroll
  for (int kb = 0; kb < 32; ++kb) {
    f16x8 af0 = *(const f16x8*)(lds + (kb * 2 + Lh) * 1024 + (0 * 32 + Lm) * 16);
    f16x8 af1 = *(const f16x8*)(lds + (kb * 2 + Lh) * 1024 + (1 * 32 + Lm) * 16);
    f16x8 bf = *(const f16x8*)(Bf + fragOff(kb, ntG, L, 0));
    acc[0] = MFMA(af0, bf, acc[0], 0, 0, 0);
    acc[1] = MFMA(af1, bf, acc[1], 0, 0, 0);
  }
#pragma unroll
  for (int mt = 0; mt < 2; ++mt)
#pragma unroll
    for (int r = 0; r < 16; ++r) {
      int k = mt64 * 64 + mt * 32 + rowOf(r, Lh);
      int n = n0 + w * 32 + Lm;
      f16 v = (f16)acc[mt][r];
      if (outP) outP[(size_t)k * 512 + n] = v;
      outF[fragOff(k >> 4, n >> 5, ((k >> 3) & 1) * 32 + (n & 31), k & 7)] = v;
    }
}

// ---------------------------------------------------------------------------
// pass1: P[t] = sum_{j=0..3} x[t-j] (W A^j). grid 2048 = (b 32) x (t 16) x (u-q 4).
// Staged x rows t0-3..t0+63 (H=3, S=67); shift so = 3-j per tap. Prefetch-2 + remap.
__global__ __launch_bounds__(256, 4) void pass1(const float* __restrict__ x,
                                                const f16* __restrict__ M0f,
                                                const f16* __restrict__ M1f,
                                                const f16* __restrict__ M2f,
                                                const f16* __restrict__ M3f,
                                                f16* __restrict__ dst) {
  const int S = 67, BUF = 8 * 67 * 16, H = 3;
  __shared__ __align__(16) char lds[2 * 8 * 67 * 16];
  const int tid = threadIdx.x;
  const int w = tid >> 6, L = tid & 63, Lm = L & 31, Lh = L >> 5;
  const int wg = xcdRemap(blockIdx.x), q = wg & 3, mtile = wg >> 2;
  const int b = mtile >> 4, t0 = (mtile & 15) * 64;
  const int ntG = q * 4 + w;
  const int p8 = tid & 7, rr = tid >> 3;   // 8 col-parts x 32 rows x 2 iters

  f16* dstB = dst + (size_t)b * PBSTRIDE;
  if (t0 == 0) {   // zero this batch's 16-row pad (q-slice) for pass2's halo reads (H=12)
    f16x8 z = {};
    *(f16x8*)(dstB + (size_t)(tid >> 4) * 512 + q * 128 + (tid & 15) * 8) = z;
  }

  float4 rA[2][2], rB[2][2], rHA[2], rHB[2];
  auto loadStage = [&](int c, int st) {
#pragma unroll
    for (int it = 0; it < 2; ++it) {
      int r = it * 32 + rr;
      const float* qp = x + ((size_t)(b * 1024 + t0 + r) * 512 + c * 64 + p8 * 8);
      rA[st][it] = *(const float4*)qp;
      rB[st][it] = *(const float4*)(qp + 4);
    }
    if (tid < 8 * H) {   // halo rows t0-3..t0-1, part tid&7, row h = tid>>3
      if (t0 > 0) {
        const float* qp = x + ((size_t)(b * 1024 + t0 - H + (tid >> 3)) * 512 + c * 64 + (tid & 7) * 8);
        rHA[st] = *(const float4*)qp;
        rHB[st] = *(const float4*)(qp + 4);
      } else {
        rHA[st] = make_float4(0.f, 0.f, 0.f, 0.f);
        rHB[st] = make_float4(0.f, 0.f, 0.f, 0.f);
      }
    }
  };
  auto dsWrite = [&](int c, int st) {
    char* B = lds + (c & 1) * BUF;
#pragma unroll
    for (int it = 0; it < 2; ++it) {
      f16x8 v;
      v[0] = (f16)rA[st][it].x; v[1] = (f16)rA[st][it].y;
      v[2] = (f16)rA[st][it].z; v[3] = (f16)rA[st][it].w;
      v[4] = (f16)rB[st][it].x; v[5] = (f16)rB[st][it].y;
      v[6] = (f16)rB[st][it].z; v[7] = (f16)rB[st][it].w;
      *(f16x8*)(B + (p8 * S + (H + it * 32 + rr)) * 16) = v;
    }
    if (tid < 8 * H) {
      f16x8 v;
      v[0] = (f16)rHA[st].x; v[1] = (f16)rHA[st].y;
      v[2] = (f16)rHA[st].z; v[3] = (f16)rHA[st].w;
      v[4] = (f16)rHB[st].x; v[5] = (f16)rHB[st].y;
      v[6] = (f16)rHB[st].z; v[7] = (f16)rHB[st].w;
      *(f16x8*)(B + ((tid & 7) * S + (tid >> 3)) * 16) = v;
    }
  };

  f32x16 acc[2] = {};
  loadStage(0, 0);
  loadStage(1, 1);
  dsWrite(0, 0); barrier_lgkm();
#pragma unroll
  for (int c = 0; c < 8; ++c) {
    if (c + 2 < 8) loadStage(c + 2, c & 1);
    const char* B = lds + (c & 1) * BUF;
#pragma unroll
    for (int kbL = 0; kbL < 4; ++kbL) {
      int kbG = c * 4 + kbL;
      f16x8 af[4][2], bf[4];
#pragma unroll
      for (int js = 0; js < 4; ++js) {
        const int so = H - js;   // tap js reads x[t-js]
#pragma unroll
        for (int mt = 0; mt < 2; ++mt)
          af[js][mt] = *(const f16x8*)(B + ((kbL * 2 + Lh) * S + (so + mt * 32 + Lm)) * 16);
      }
      bf[0] = *(const f16x8*)(M0f + fragOff(kbG, ntG, L, 0));
      bf[1] = *(const f16x8*)(M1f + fragOff(kbG, ntG, L, 0));
      bf[2] = *(const f16x8*)(M2f + fragOff(kbG, ntG, L, 0));
      bf[3] = *(const f16x8*)(M3f + fragOff(kbG, ntG, L, 0));
#pragma unroll
      for (int js = 0; js < 4; ++js)
#pragma unroll
        for (int mt = 0; mt < 2; ++mt)
          acc[mt] = MFMA(af[js][mt], bf[js], acc[mt], 0, 0, 0);
    }
    if (c + 1 < 8) { dsWrite(c + 1, (c + 1) & 1); barrier_lgkm(); }
  }
  const int u = ntG * 32 + Lm;
#pragma unroll
  for (int mt = 0; mt < 2; ++mt)
#pragma unroll
    for (int r = 0; r < 16; ++r) {
      int i = 16 + t0 + mt * 32 + rowOf(r, Lh);
      dstB[(size_t)i * 512 + u] = (f16)acc[mt][r];
    }
}

// ---------------------------------------------------------------------------
// pass2: OUT[t] = P[t] + P[t-4]A4 + P[t-8]A8 + P[t-12]A12, f32 out.
// Staged P rows t0-12..t0+63 (H=12, S=77); tap-0 via staged-tile acc-init.
__global__ __launch_bounds__(256, 4) void pass2(const f16* __restrict__ src,
                                                const f16* __restrict__ A4f,
                                                const f16* __restrict__ A8f,
                                                const f16* __restrict__ A12f,
                                                float* __restrict__ out) {
  const int S = 77, BUF = 8 * 77 * 16, H = 12;
  __shared__ __align__(16) char lds[2 * 8 * 77 * 16];
  const int tid = threadIdx.x;
  const int w = tid >> 6, L = tid & 63, Lm = L & 31, Lh = L >> 5;
  const int wg = xcdRemap(blockIdx.x), q = wg & 3, mtile = wg >> 2;
  const int b = mtile >> 4, t0 = (mtile & 15) * 64;
  const int ntG = q * 4 + w;
  const int p4 = tid & 3, rr = tid >> 2;   // 4 parts(32B) x 64 rows
  const f16* srcB = src + (size_t)b * PBSTRIDE;

  f16x8 sreg[2][2], hreg[2][2];
  auto loadStage = [&](int c, int st) {
    const f16* qp = srcB + ((size_t)(16 + t0 + rr) * 512 + c * 64 + p4 * 16);
    sreg[st][0] = *(const f16x8*)qp;
    sreg[st][1] = *(const f16x8*)(qp + 8);
    if (tid < 4 * H) {   // halo rows t0-12..t0-1 (pad rows are zeroed for t0==0)
      const f16* qh = srcB + ((size_t)(16 + t0 - H + (tid >> 2)) * 512 + c * 64 + (tid & 3) * 16);
      hreg[st][0] = *(const f16x8*)qh;
      hreg[st][1] = *(const f16x8*)(qh + 8);
    }
  };
  auto dsWrite = [&](int c, int st) {
    char* B = lds + (c & 1) * BUF;
    int slot = H + rr;
    *(f16x8*)(B + ((2 * p4) * S + slot) * 16) = sreg[st][0];
    *(f16x8*)(B + ((2 * p4 + 1) * S + slot) * 16) = sreg[st][1];
    if (tid < 4 * H) {
      *(f16x8*)(B + ((2 * (tid & 3)) * S + (tid >> 2)) * 16) = hreg[st][0];
      *(f16x8*)(B + ((2 * (tid & 3) + 1) * S + (tid >> 2)) * 16) = hreg[st][1];
    }
  };

  f32x16 acc[2] = {};
  const int myChunk = ntG >> 1;
  loadStage(0, 0);
  loadStage(1, 1);
  dsWrite(0, 0); barrier_lgkm();
#pragma unroll
  for (int c = 0; c < 8; ++c) {
    if (c + 2 < 8) loadStage(c + 2, c & 1);
    const char* B = lds + (c & 1) * BUF;
    if (c == myChunk) {   // tap-0 init from the staged tile
      int kb8 = (ntG & 1) * 4 + (Lm >> 3);
#pragma unroll
      for (int mt = 0; mt < 2; ++mt)
#pragma unroll
        for (int r = 0; r < 16; ++r) {
          int slot = H + mt * 32 + rowOf(r, Lh);
          acc[mt][r] += (float)(*(const f16*)(B + (kb8 * S + slot) * 16 + (Lm & 7) * 2));
        }
    }
#pragma unroll
    for (int kbL = 0; kbL < 4; ++kbL) {
      int kbG = c * 4 + kbL;
#pragma unroll
      for (int js = 0; js < 3; ++js) {
        const f16* Ms = (js == 0) ? A4f : (js == 1) ? A8f : A12f;
        const int so = (js == 0) ? 8 : (js == 1) ? 4 : 0;   // H - shift (4,8,12)
        f16x8 af[2], bf;
#pragma unroll
        for (int mt = 0; mt < 2; ++mt)
          af[mt] = *(const f16x8*)(B + ((kbL * 2 + Lh) * S + (so + mt * 32 + Lm)) * 16);
        bf = *(const f16x8*)(Ms + fragOff(kbG, ntG, L, 0));
#pragma unroll
        for (int mt = 0; mt < 2; ++mt)
          acc[mt] = MFMA(af[mt], bf, acc[mt], 0, 0, 0);
      }
    }
    if (c + 1 < 8) { dsWrite(c + 1, (c + 1) & 1); barrier_lgkm(); }
  }
  const int u = ntG * 32 + Lm;
#pragma unroll
  for (int mt = 0; mt < 2; ++mt)
#pragma unroll
    for (int r = 0; r < 16; ++r) {
      int t = t0 + mt * 32 + rowOf(r, Lh);
      out[(size_t)(b * 1024 + t) * 512 + u] = acc[mt][r];
    }
}

// ---------------------------------------------------------------------------
extern "C" void kernel_launch(void* const* d_in, const int* in_sizes, int n_in,
                              void* d_out, int out_size, void* d_ws, size_t ws_size,
                              hipStream_t stream) {
  (void)in_sizes; (void)n_in; (void)out_size; (void)ws_size;
  const float* x = (const float*)d_in[0];
  const float* W = (const float*)d_in[1];
  const float* A = (const float*)d_in[2];
  float* out = (float*)d_out;

  char* ws = (char*)d_ws;
  const size_t HK = 512 << 10;
  f16* Wf   = (f16*)(ws + 0 * HK);
  f16* WAf  = (f16*)(ws + 1 * HK);
  f16* WA2f = (f16*)(ws + 2 * HK);
  f16* WA3f = (f16*)(ws + 3 * HK);
  f16* A4f  = (f16*)(ws + 4 * HK);
  f16* A8f  = (f16*)(ws + 5 * HK);
  f16* A12f = (f16*)(ws + 6 * HK);
  f16* Wh   = (f16*)(ws + 7 * HK);   // reused as A8p after L1 (Wh dead)
  f16* Ah   = (f16*)(ws + 8 * HK);
  f16* Ahf  = (f16*)(ws + 9 * HK);
  f16* WAp  = (f16*)(ws + 10 * HK);
  f16* A2p  = (f16*)(ws + 11 * HK);
  f16* A2f  = (f16*)(ws + 12 * HK);
  f16* A4p  = (f16*)(ws + 13 * HK);
  f16* bufP = (f16*)(ws + 14 * HK);  // P, ~34.1MB (pass2 reads while writing f32 to d_out)
  f16* A8p  = Wh;

  Kc1<<<128, 256, 0, stream>>>(W, A, Wh, Ah, Wf, Ahf);
  // L1: WA = W*A ; A2 = A*A
  Gk3<<<64, 256, 0, stream>>>(Wh, Ahf, WAp, WAf, Ah, Ahf, A2p, A2f,
                              nullptr, nullptr, nullptr, nullptr);
  // L2: WA2 = WA*A ; WA3 = WA*A2 ; A4 = A2*A2
  Gk3<<<96, 256, 0, stream>>>(WAp, Ahf, nullptr, WA2f, WAp, A2f, nullptr, WA3f,
                              A2p, A2f, A4p, A4f);
  pass1<<<2048, 256, 0, stream>>>(x, Wf, WAf, WA2f, WA3f, bufP);
  // L3: A8 = A4*A4
  Gk3<<<32, 256, 0, stream>>>(A4p, A4f, A8p, A8f, nullptr, nullptr, nullptr, nullptr,
                              nullptr, nullptr, nullptr, nullptr);
  // L4: A12 = A8*A4
  Gk3<<<32, 256, 0, stream>>>(A8p, A4f, nullptr, A12f, nullptr, nullptr, nullptr, nullptr,
                              nullptr, nullptr, nullptr, nullptr);
  pass2<<<2048, 256, 0, stream>>>(bufP, A4f, A8f, A12f, out);
}